// Round 4
// baseline (5599.834 us; speedup 1.0000x reference)
//
#include <hip/hip_runtime.h>

typedef short short8 __attribute__((ext_vector_type(8)));
typedef float f32x4 __attribute__((ext_vector_type(4)));

#define T_STEPS 512
#define BATCH   128
#define EMBD    512
#define HID     1024
#define NWG     128
#define NTHR    1024

// ---- workspace layout (bytes) ----
#define SLOT_OFF    0
#define SLOT_STRIDE 16                        // uints per slot (64 B padding)
#define SLOT_BYTES  (NWG * SLOT_STRIDE * 4)   // 8192
#define H_OFF     SLOT_BYTES
#define H_ELEMS   131072                      // ushort per h buffer (128*1024)
#define WH_OFF    (H_OFF + 2*H_ELEMS*2)
#define WH_ELEMS  (NWG*64*64*8)               // 4,194,304 ushort
#define WI_OFF    (WH_OFF + WH_ELEMS*2)
#define WI_ELEMS  (NWG*32*64*8)               // 2,097,152 ushort
#define BS_OFF    (WI_OFF + WI_ELEMS*2)
#define BS_ELEMS  (NWG*32)                    // float
#define PT_OFF    (BS_OFF + BS_ELEMS*4)
#define PT_ELEMS  (NWG*BATCH*2)               // float
#define EMB_OFF   (PT_OFF + PT_ELEMS*4)
#define EMB_ELEMS ((size_t)T_STEPS*16*8*64*8) // 33,554,432 ushort
#define WS_NEEDED (EMB_OFF + EMB_ELEMS*2)

__device__ __forceinline__ unsigned short f2b(float f) {
    unsigned u = __builtin_bit_cast(unsigned, f);
    u += 0x7FFFu + ((u >> 16) & 1u);
    return (unsigned short)(u >> 16);
}

__device__ __forceinline__ uint4 pack8(float4 a, float4 b) {
    uint4 r;
    r.x = (unsigned)f2b(a.x) | ((unsigned)f2b(a.y) << 16);
    r.y = (unsigned)f2b(a.z) | ((unsigned)f2b(a.w) << 16);
    r.z = (unsigned)f2b(b.x) | ((unsigned)f2b(b.y) << 16);
    r.w = (unsigned)f2b(b.z) | ((unsigned)f2b(b.w) << 16);
    return r;
}

__device__ __forceinline__ float fsig(float x) {
    float e = __expf(-fabsf(x));
    float r = 1.f / (1.f + e);
    return x >= 0.f ? r : 1.f - r;
}
__device__ __forceinline__ float ftanh_(float x) {
    float e = __expf(-2.f * fabsf(x));
    float r = (1.f - e) / (1.f + e);
    return x >= 0.f ? r : -r;
}

// W_hh [4096,1024] f32 -> bf16 fragment chunks: wh_arr[j][chunk=ks*2+nt][lane][8]
__global__ void prep_wh(const float* __restrict__ w_hh, unsigned short* __restrict__ wh_arr) {
    int gid = blockIdx.x * blockDim.x + threadIdx.x;   // < 128*64*64
    int l  = gid & 63;
    int c  = (gid >> 6) & 63;
    int j  = gid >> 12;
    int ks = c >> 1, nt = c & 1;
    int lr = nt * 16 + (l & 15);                       // local gate row 0..31
    int grow = (lr >> 3) * HID + j * 8 + (lr & 7);     // global gate row
    int k = ks * 32 + (l >> 4) * 8;
    const float4* src = reinterpret_cast<const float4*>(w_hh + (size_t)grow * HID + k);
    *reinterpret_cast<uint4*>(wh_arr + (size_t)gid * 8) = pack8(src[0], src[1]);
}

// W_ih [4096,512] f32 -> wi_arr[j][chunk=ks*2+nt][lane][8]
__global__ void prep_wi(const float* __restrict__ w_ih, unsigned short* __restrict__ wi_arr) {
    int gid = blockIdx.x * blockDim.x + threadIdx.x;   // < 128*32*64
    int l  = gid & 63;
    int c  = (gid >> 6) & 31;
    int j  = gid >> 11;
    int ks = c >> 1, nt = c & 1;
    int lr = nt * 16 + (l & 15);
    int grow = (lr >> 3) * HID + j * 8 + (lr & 7);
    int k = ks * 32 + (l >> 4) * 8;
    const float4* src = reinterpret_cast<const float4*>(w_ih + (size_t)grow * EMBD + k);
    *reinterpret_cast<uint4*>(wi_arr + (size_t)gid * 8) = pack8(src[0], src[1]);
}

__global__ void prep_bsum(const float* __restrict__ b_ih, const float* __restrict__ b_hh,
                          float* __restrict__ bs) {
    int gid = blockIdx.x * blockDim.x + threadIdx.x;   // < 128*32
    int lr = gid & 31, j = gid >> 5;
    int grow = (lr >> 3) * HID + j * 8 + (lr & 7);
    bs[gid] = b_ih[grow] + b_hh[grow];
}

// embedded bf16 fragment chunks: emb_arr[t][ks][mt][lane][8]
__global__ void prep_emb(const int* __restrict__ x, const float* __restrict__ emb,
                         unsigned short* __restrict__ emb_arr) {
    int gid = blockIdx.x * blockDim.x + threadIdx.x;   // < 512*16*8*64
    int l  = gid & 63;
    int mt = (gid >> 6) & 7;
    int ks = (gid >> 9) & 15;
    int t  = gid >> 13;
    int b  = mt * 16 + (l & 15);
    int k  = ks * 32 + (l >> 4) * 8;
    int tok = x[t * BATCH + b];
    const float4* src = reinterpret_cast<const float4*>(emb + (size_t)tok * EMBD + k);
    *reinterpret_cast<uint4*>(emb_arr + (size_t)gid * 8) = pack8(src[0], src[1]);
}

__global__ __launch_bounds__(NTHR) void lstm_main(
    const unsigned short* __restrict__ wh_arr,
    const unsigned short* __restrict__ wi_arr,
    const float* __restrict__ bs_arr,
    const unsigned short* __restrict__ emb_arr,
    unsigned short* __restrict__ h_arr,
    const float* __restrict__ fc_w,
    float* __restrict__ partials,
    unsigned* __restrict__ slots)
{
    __shared__ __align__(16) unsigned short wis[32 * 64 * 8];   // 32 KB (emb B operands)
    __shared__ __align__(16) float gbuf[4][BATCH * 36];         // 73.7 KB, stride 36
    __shared__ float bss[32];

    const int tid = threadIdx.x;
    const int j   = blockIdx.x;

    {   // one-time LDS fill: emb-part weights + bias
        const uint4* s2 = reinterpret_cast<const uint4*>(wi_arr + (size_t)j * 16384);
        uint4* d2 = reinterpret_cast<uint4*>(wis);
        for (int i = tid; i < 2048; i += NTHR) d2[i] = s2[i];
        if (tid < 32) bss[tid] = bs_arr[j * 32 + tid];
    }

    const int lane = tid & 63;
    const int wave = tid >> 6;     // 0..15
    const int mq   = wave >> 2;    // 0..3  -> m-tiles {2mq, 2mq+1}
    const int kq   = wave & 3;     // 0..3  -> h-ks [8kq,8kq+8), emb-ks [4kq,4kq+4)
    const int mt0  = mq * 2, mt1 = mq * 2 + 1;

    // h-part B operands: persistent registers (loop-invariant across all 512 steps)
    short8 bh[8][2];
    {
        const unsigned short* wsrc = wh_arr + (size_t)j * 32768;
        #pragma unroll
        for (int s = 0; s < 8; ++s) {
            int ks = kq * 8 + s;
            bh[s][0] = *reinterpret_cast<const short8*>(wsrc + ((ks * 2 + 0) * 64 + lane) * 8);
            bh[s][1] = *reinterpret_cast<const short8*>(wsrc + ((ks * 2 + 1) * 64 + lane) * 8);
        }
    }
    __syncthreads();

    // pointwise ownership: one (batch, hcol) pair per thread
    const int pb   = tid >> 3;         // 0..127
    const int phc  = tid & 7;          // 0..7
    const int pcol = j * 8 + phc;      // global h column
    const int hks   = pcol >> 5;
    const int hlane = (((pcol & 31) >> 3) << 4) | (pb & 15);
    const int hmt   = pb >> 4;
    const int hidx  = ((hks * 8 + hmt) * 64 + hlane) * 8 + (pcol & 7);

    float c = 0.f, lasth = 0.f;

    for (int t = 0; t < T_STEPS; ++t) {
        f32x4 a00 = {0.f,0.f,0.f,0.f}, a01 = {0.f,0.f,0.f,0.f};
        f32x4 a10 = {0.f,0.f,0.f,0.f}, a11 = {0.f,0.f,0.f,0.f};

        // ---- emb part first: independent of h / barrier, overlaps arrival skew ----
        const unsigned short* ebuf = emb_arr + (size_t)t * 65536;
        #pragma unroll
        for (int e = 0; e < 4; ++e) {
            int eks = kq * 4 + e;
            short8 x0 = *reinterpret_cast<const short8*>(ebuf + ((eks * 8 + mt0) * 64 + lane) * 8);
            short8 x1 = *reinterpret_cast<const short8*>(ebuf + ((eks * 8 + mt1) * 64 + lane) * 8);
            short8 w0 = *reinterpret_cast<const short8*>(wis + ((eks * 2 + 0) * 64 + lane) * 8);
            short8 w1 = *reinterpret_cast<const short8*>(wis + ((eks * 2 + 1) * 64 + lane) * 8);
            a00 = __builtin_amdgcn_mfma_f32_16x16x32_bf16(x0, w0, a00, 0, 0, 0);
            a01 = __builtin_amdgcn_mfma_f32_16x16x32_bf16(x0, w1, a01, 0, 0, 0);
            a10 = __builtin_amdgcn_mfma_f32_16x16x32_bf16(x1, w0, a10, 0, 0, 0);
            a11 = __builtin_amdgcn_mfma_f32_16x16x32_bf16(x1, w1, a11, 0, 0, 0);
        }

        // ---- wait for h_t (all WGs arrived with value >= t); t=0: h=0, skip ----
        if (t > 0) {
            if (tid < NWG) {
                while (__hip_atomic_load(&slots[tid * SLOT_STRIDE],
                                         __ATOMIC_RELAXED, __HIP_MEMORY_SCOPE_AGENT) < (unsigned)t) {}
            }
            __syncthreads();
            if (tid == 0) {
                (void)__hip_atomic_load(&slots[0], __ATOMIC_ACQUIRE, __HIP_MEMORY_SCOPE_AGENT);
            }
            __syncthreads();

            const unsigned short* hbuf = h_arr + (t & 1) * H_ELEMS;
            #pragma unroll
            for (int s = 0; s < 8; ++s) {
                int ks = kq * 8 + s;
                short8 x0 = *reinterpret_cast<const short8*>(hbuf + ((ks * 8 + mt0) * 64 + lane) * 8);
                short8 x1 = *reinterpret_cast<const short8*>(hbuf + ((ks * 8 + mt1) * 64 + lane) * 8);
                a00 = __builtin_amdgcn_mfma_f32_16x16x32_bf16(x0, bh[s][0], a00, 0, 0, 0);
                a01 = __builtin_amdgcn_mfma_f32_16x16x32_bf16(x0, bh[s][1], a01, 0, 0, 0);
                a10 = __builtin_amdgcn_mfma_f32_16x16x32_bf16(x1, bh[s][0], a10, 0, 0, 0);
                a11 = __builtin_amdgcn_mfma_f32_16x16x32_bf16(x1, bh[s][1], a11, 0, 0, 0);
            }
        }

        {   // D frag -> gbuf[kq]  (row m = (lane>>4)*4+jj, col n = lane&15)
            float* g = &gbuf[kq][0];
            const int col = lane & 15;
            const int bl0 = mt0 * 16 + ((lane >> 4) << 2);
            const int bl1 = mt1 * 16 + ((lane >> 4) << 2);
            #pragma unroll
            for (int jj = 0; jj < 4; ++jj) {
                g[(bl0 + jj) * 36 + col]      = a00[jj];
                g[(bl0 + jj) * 36 + 16 + col] = a01[jj];
                g[(bl1 + jj) * 36 + col]      = a10[jj];
                g[(bl1 + jj) * 36 + 16 + col] = a11[jj];
            }
        }
        __syncthreads();
        {   // LSTM pointwise: sum 4 kq partials; i,f,g,o at lr = {hc, 8+hc, 16+hc, 24+hc}
            float xi = bss[phc], xf = bss[8 + phc], xg = bss[16 + phc], xo = bss[24 + phc];
            #pragma unroll
            for (int q = 0; q < 4; ++q) {
                xi += gbuf[q][pb * 36 + phc];
                xf += gbuf[q][pb * 36 + 8 + phc];
                xg += gbuf[q][pb * 36 + 16 + phc];
                xo += gbuf[q][pb * 36 + 24 + phc];
            }
            float ig = fsig(xi), fg = fsig(xf), gg = ftanh_(xg), og = fsig(xo);
            c = fg * c + ig * gg;
            float h = og * ftanh_(c);
            lasth = h;
            h_arr[((t + 1) & 1) * H_ELEMS + hidx] = f2b(h);
        }
        __syncthreads();   // gbuf consumed + h stores issued before the release below
        if (tid == 0) {
            __hip_atomic_store(&slots[j * SLOT_STRIDE], (unsigned)(t + 1),
                               __ATOMIC_RELEASE, __HIP_MEMORY_SCOPE_AGENT);
        }
    }

    {   // deterministic per-WG partial of out = h_T @ fc_w^T  (reduce over 8 lanes = 8 hcols)
        float v0 = lasth * fc_w[0 * HID + pcol];
        float v1 = lasth * fc_w[1 * HID + pcol];
        #pragma unroll
        for (int m = 1; m < 8; m <<= 1) {
            v0 += __shfl_xor(v0, m);
            v1 += __shfl_xor(v1, m);
        }
        if (phc == 0) {
            partials[(j * BATCH + pb) * 2 + 0] = v0;
            partials[(j * BATCH + pb) * 2 + 1] = v1;
        }
    }
}

__global__ void finalize(const float* __restrict__ partials, const float* __restrict__ fc_b,
                         float* __restrict__ out) {
    int tid = threadIdx.x;             // 256
    int b = tid >> 1, o = tid & 1;
    float s = fc_b[o];
    for (int j = 0; j < NWG; ++j) s += partials[(j * BATCH + b) * 2 + o];
    out[b * 2 + o] = s;
}

extern "C" void kernel_launch(void* const* d_in, const int* in_sizes, int n_in,
                              void* d_out, int out_size, void* d_ws, size_t ws_size,
                              hipStream_t stream) {
    const int*   x    = (const int*)d_in[0];
    const float* emb  = (const float*)d_in[1];
    const float* w_ih = (const float*)d_in[2];
    const float* w_hh = (const float*)d_in[3];
    const float* b_ih = (const float*)d_in[4];
    const float* b_hh = (const float*)d_in[5];
    const float* fc_w = (const float*)d_in[6];
    const float* fc_b = (const float*)d_in[7];
    float* out = (float*)d_out;
    char* ws = (char*)d_ws;

    if (ws_size < WS_NEEDED) {
        (void)hipMemsetAsync(d_out, 0xFF, (size_t)out_size * sizeof(float), stream);
        return;
    }

    unsigned*       slots   = (unsigned*)(ws + SLOT_OFF);
    unsigned short* h_arr   = (unsigned short*)(ws + H_OFF);
    unsigned short* wh_arr  = (unsigned short*)(ws + WH_OFF);
    unsigned short* wi_arr  = (unsigned short*)(ws + WI_OFF);
    float*          bs_arr  = (float*)(ws + BS_OFF);
    float*          pt_arr  = (float*)(ws + PT_OFF);
    unsigned short* emb_arr = (unsigned short*)(ws + EMB_OFF);

    // zero the arrival slots (h buffers need no init: t=0 skips the h-MFMA)
    (void)hipMemsetAsync(ws, 0, SLOT_BYTES, stream);

    prep_wh  <<<2048, 256, 0, stream>>>(w_hh, wh_arr);
    prep_wi  <<<1024, 256, 0, stream>>>(w_ih, wi_arr);
    prep_bsum<<<16,   256, 0, stream>>>(b_ih, b_hh, bs_arr);
    prep_emb <<<16384,256, 0, stream>>>(x, emb, emb_arr);
    lstm_main<<<NWG, NTHR, 0, stream>>>(wh_arr, wi_arr, bs_arr, emb_arr, h_arr,
                                        fc_w, pt_arr, slots);
    finalize <<<1, 256, 0, stream>>>(pt_arr, fc_b, out);
}

// Round 5
// 3666.808 us; speedup vs baseline: 1.5272x; 1.5272x over previous
//
#include <hip/hip_runtime.h>

typedef short short8 __attribute__((ext_vector_type(8)));
typedef float f32x4 __attribute__((ext_vector_type(4)));
typedef unsigned long long u64;

#define T_STEPS 512
#define BATCH   128
#define EMBD    512
#define HID     1024
#define NWG     256
#define NTHR    1024
#define NGROUP  8
#define WPG     32     // workgroups per group

// ---- workspace layout (bytes) ----
#define SLOT_STRIDE 16
#define SLOT_BYTES  (NWG * SLOT_STRIDE * 4)       // 16384
#define H_OFF     SLOT_BYTES
#define H_BYTES   (NGROUP * 2 * 16384 * 2)        // 524288 (16384 ushort per group-buf)
#define WH_OFF    (H_OFF + H_BYTES)               // 540672
#define WH_BYTES  (32u*32u*8u*64u*8u*2u)          // 8388608
#define WI_OFF    (WH_OFF + WH_BYTES)             // 8929280
#define WI_BYTES  (32u*16u*8u*64u*8u*2u)          // 4194304
#define BS_OFF    (WI_OFF + WI_BYTES)             // 13123584
#define BS_BYTES  (4096 * 4)
#define PT_OFF    (BS_OFF + BS_BYTES)             // 13139968
#define PT_BYTES  (BATCH * 32 * 2 * 4)            // 32768
#define EMB_OFF   (PT_OFF + PT_BYTES)             // 13172736
#define EMB_BYTES ((size_t)T_STEPS*16*8*64*8*2)   // 67108864
#define WS_NEEDED (EMB_OFF + EMB_BYTES)

__device__ __forceinline__ unsigned short f2b(float f) {
    unsigned u = __builtin_bit_cast(unsigned, f);
    u += 0x7FFFu + ((u >> 16) & 1u);
    return (unsigned short)(u >> 16);
}

__device__ __forceinline__ uint4 pack8(float4 a, float4 b) {
    uint4 r;
    r.x = (unsigned)f2b(a.x) | ((unsigned)f2b(a.y) << 16);
    r.y = (unsigned)f2b(a.z) | ((unsigned)f2b(a.w) << 16);
    r.z = (unsigned)f2b(b.x) | ((unsigned)f2b(b.y) << 16);
    r.w = (unsigned)f2b(b.z) | ((unsigned)f2b(b.w) << 16);
    return r;
}

__device__ __forceinline__ float fsig(float x) {
    float e = __expf(-fabsf(x));
    float r = 1.f / (1.f + e);
    return x >= 0.f ? r : 1.f - r;
}
__device__ __forceinline__ float ftanh_(float x) {
    float e = __expf(-2.f * fabsf(x));
    float r = (1.f - e) / (1.f + e);
    return x >= 0.f ? r : -r;
}

// W_hh [4096,1024] -> wh_arr[w][ks(32)][nq(8)][lane][8]
__global__ void prep_wh(const float* __restrict__ w_hh, unsigned short* __restrict__ wh_arr) {
    int gid = blockIdx.x * blockDim.x + threadIdx.x;   // < 32*32*8*64 = 524288
    int l  = gid & 63;
    int nq = (gid >> 6) & 7;
    int ks = (gid >> 9) & 31;
    int w  = gid >> 14;
    int lr = nq * 16 + (l & 15);                       // 0..127
    int grow = (lr >> 5) * HID + w * 32 + (lr & 31);   // gate*1024 + col
    int k = ks * 32 + (l >> 4) * 8;
    const float4* src = reinterpret_cast<const float4*>(w_hh + (size_t)grow * HID + k);
    *reinterpret_cast<uint4*>(wh_arr + (size_t)gid * 8) = pack8(src[0], src[1]);
}

// W_ih [4096,512] -> wi_arr[w][eks(16)][nq(8)][lane][8]
__global__ void prep_wi(const float* __restrict__ w_ih, unsigned short* __restrict__ wi_arr) {
    int gid = blockIdx.x * blockDim.x + threadIdx.x;   // < 32*16*8*64 = 262144
    int l  = gid & 63;
    int nq = (gid >> 6) & 7;
    int eks = (gid >> 9) & 15;
    int w  = gid >> 13;
    int lr = nq * 16 + (l & 15);
    int grow = (lr >> 5) * HID + w * 32 + (lr & 31);
    int k = eks * 32 + (l >> 4) * 8;
    const float4* src = reinterpret_cast<const float4*>(w_ih + (size_t)grow * EMBD + k);
    *reinterpret_cast<uint4*>(wi_arr + (size_t)gid * 8) = pack8(src[0], src[1]);
}

__global__ void prep_bsum(const float* __restrict__ b_ih, const float* __restrict__ b_hh,
                          float* __restrict__ bs) {
    int gid = blockIdx.x * blockDim.x + threadIdx.x;   // < 4096
    int w = gid >> 7, lr = gid & 127;
    int grow = (lr >> 5) * HID + w * 32 + (lr & 31);
    bs[gid] = b_ih[grow] + b_hh[grow];
}

// embedded bf16 fragment chunks: emb_arr[t][eks(16)][mt(8)][lane][8]  (mt == group)
__global__ void prep_emb(const int* __restrict__ x, const float* __restrict__ emb,
                         unsigned short* __restrict__ emb_arr) {
    int gid = blockIdx.x * blockDim.x + threadIdx.x;   // < 512*16*8*64
    int l  = gid & 63;
    int mt = (gid >> 6) & 7;
    int ks = (gid >> 9) & 15;
    int t  = gid >> 13;
    int b  = mt * 16 + (l & 15);
    int k  = ks * 32 + (l >> 4) * 8;
    int tok = x[t * BATCH + b];
    const float4* src = reinterpret_cast<const float4*>(emb + (size_t)tok * EMBD + k);
    *reinterpret_cast<uint4*>(emb_arr + (size_t)gid * 8) = pack8(src[0], src[1]);
}

__global__ __launch_bounds__(NTHR) void lstm_main(
    const unsigned short* __restrict__ wh_arr,
    const unsigned short* __restrict__ wi_arr,
    const float* __restrict__ bs_arr,
    const unsigned short* __restrict__ emb_arr,
    unsigned short* __restrict__ h_arr,
    const float* __restrict__ fc_w,
    float* __restrict__ partials,
    unsigned* __restrict__ slots)
{
    __shared__ __align__(16) unsigned short wis[16 * 8 * 64 * 8];  // 131072 B
    __shared__ __align__(16) char ovl[32768];                      // stage (32 KB) / gbuf (16.5 KB) overlay
    float*  gbuf   = reinterpret_cast<float*>(ovl);                // [2][16][132]
    unsigned short* stage = reinterpret_cast<unsigned short*>(ovl);// [32][64][8]
    u64*    stage64 = reinterpret_cast<u64*>(ovl);

    const int tid  = threadIdx.x;
    const int wgid = blockIdx.x;
    const int g = wgid >> 5;      // group 0..7 (batch rows 16g..16g+15)
    const int w = wgid & 31;      // gate-slice 0..31 (h cols 32w..32w+31)

    {   // one-time LDS fill of W_ih slice
        const uint4* s2 = reinterpret_cast<const uint4*>(wi_arr + (size_t)w * 65536);
        uint4* d2 = reinterpret_cast<uint4*>(wis);
        for (int i = tid; i < 8192; i += NTHR) d2[i] = s2[i];
    }

    const int lane = tid & 63;
    const int wave = tid >> 6;    // 0..15
    const int nq   = wave >> 1;   // n-tile 0..7 (16 gate rows each)
    const int kq   = wave & 1;    // k-half

    // W_hh B-fragments: persistent registers (64 VGPRs)
    short8 bh[16];
    #pragma unroll
    for (int s = 0; s < 16; ++s) {
        int ks = kq * 16 + s;
        bh[s] = *reinterpret_cast<const short8*>(wh_arr + (size_t)(((w * 32 + ks) * 8 + nq) * 64 + lane) * 8);
    }

    // pointwise ownership: tid<256 -> (pb, col pair c0=2cp, c1=2cp+1)
    const int pb = tid >> 4;      // 0..15 (valid when tid<256)
    const int cp = tid & 15;
    const int c0 = cp * 2, c1 = cp * 2 + 1;
    float bi0[4], bi1[4];
    if (tid < 256) {
        #pragma unroll
        for (int gm = 0; gm < 4; ++gm) {
            bi0[gm] = bs_arr[w * 128 + gm * 32 + c0];
            bi1[gm] = bs_arr[w * 128 + gm * 32 + c1];
        }
    }
    __syncthreads();

    const int lrD   = nq * 16 + (lane & 15);      // D-frag gate row
    const int rbase = (lane >> 4) * 4;            // D-frag batch row base
    // h store slot for pointwise: ks=w, lane2, elem pair
    const int lane2 = ((cp >> 2) << 4) | pb;
    const int hidx32 = (w * 64 + lane2) * 4 + (cp & 3);

    float c0s = 0.f, c1s = 0.f, h0r = 0.f, h1r = 0.f;

    for (int t = 0; t < T_STEPS; ++t) {
        f32x4 acc = {0.f, 0.f, 0.f, 0.f};

        // ---- emb part: independent of h, overlaps barrier skew ----
        const unsigned short* ebuf = emb_arr + (size_t)t * 65536;
        #pragma unroll
        for (int s = 0; s < 8; ++s) {
            int eks = kq * 8 + s;
            short8 a  = *reinterpret_cast<const short8*>(ebuf + ((eks * 8 + g) * 64 + lane) * 8);
            short8 bw = *reinterpret_cast<const short8*>(wis + ((eks * 8 + nq) * 64 + lane) * 8);
            acc = __builtin_amdgcn_mfma_f32_16x16x32_bf16(a, bw, acc, 0, 0, 0);
        }

        if (t > 0) {
            // group barrier: h_t published by all 32 group WGs
            if (tid < WPG) {
                while (__hip_atomic_load(&slots[(g * WPG + tid) * SLOT_STRIDE],
                                         __ATOMIC_RELAXED, __HIP_MEMORY_SCOPE_AGENT) < (unsigned)t) {}
            }
            __syncthreads();
            asm volatile("" ::: "memory");
            // stage group h (32 KB) into LDS via LLC-bypass loads
            const u64* hs = reinterpret_cast<const u64*>(h_arr + (size_t)(g * 2 + (t & 1)) * 16384);
            #pragma unroll
            for (int q = 0; q < 4; ++q) {
                u64 v = __hip_atomic_load(hs + q * 1024 + tid, __ATOMIC_RELAXED, __HIP_MEMORY_SCOPE_AGENT);
                stage64[q * 1024 + tid] = v;
            }
            __syncthreads();
            #pragma unroll
            for (int s = 0; s < 16; ++s) {
                int ks = kq * 16 + s;
                short8 a = *reinterpret_cast<const short8*>(stage + (ks * 64 + lane) * 8);
                acc = __builtin_amdgcn_mfma_f32_16x16x32_bf16(a, bh[s], acc, 0, 0, 0);
            }
        }
        __syncthreads();   // all stage reads done before gbuf overwrites the overlay

        #pragma unroll
        for (int jj = 0; jj < 4; ++jj)
            gbuf[kq * 2112 + (rbase + jj) * 132 + lrD] = acc[jj];
        __syncthreads();

        if (tid < 256) {   // pointwise for (pb, c0) and (pb, c1)
            const float* g0 = gbuf + pb * 132;
            const float* g1 = gbuf + 2112 + pb * 132;
            float xi0 = g0[c0]      + g1[c0]      + bi0[0];
            float xf0 = g0[32 + c0] + g1[32 + c0] + bi0[1];
            float xg0 = g0[64 + c0] + g1[64 + c0] + bi0[2];
            float xo0 = g0[96 + c0] + g1[96 + c0] + bi0[3];
            float xi1 = g0[c1]      + g1[c1]      + bi1[0];
            float xf1 = g0[32 + c1] + g1[32 + c1] + bi1[1];
            float xg1 = g0[64 + c1] + g1[64 + c1] + bi1[2];
            float xo1 = g0[96 + c1] + g1[96 + c1] + bi1[3];
            float i0 = fsig(xi0), f0 = fsig(xf0), gg0 = ftanh_(xg0), o0 = fsig(xo0);
            float i1 = fsig(xi1), f1 = fsig(xf1), gg1 = ftanh_(xg1), o1 = fsig(xo1);
            c0s = f0 * c0s + i0 * gg0;
            c1s = f1 * c1s + i1 * gg1;
            h0r = o0 * ftanh_(c0s);
            h1r = o1 * ftanh_(c1s);
            unsigned pk = (unsigned)f2b(h0r) | ((unsigned)f2b(h1r) << 16);
            unsigned* hd = reinterpret_cast<unsigned*>(h_arr + (size_t)(g * 2 + ((t + 1) & 1)) * 16384);
            __hip_atomic_store(hd + hidx32, pk, __ATOMIC_RELAXED, __HIP_MEMORY_SCOPE_AGENT);
        }
        __syncthreads();   // drains all waves' outstanding h stores (vmcnt) before release
        if (tid == 0) {
            __hip_atomic_store(&slots[(g * WPG + w) * SLOT_STRIDE], (unsigned)(t + 1),
                               __ATOMIC_RELEASE, __HIP_MEMORY_SCOPE_AGENT);
        }
    }

    if (tid < 256) {   // FC partial: this thread's 2 cols, reduce over cp (16 lanes)
        int col0 = w * 32 + c0, col1 = w * 32 + c1;
        float v0 = h0r * fc_w[col0] + h1r * fc_w[col1];
        float v1 = h0r * fc_w[HID + col0] + h1r * fc_w[HID + col1];
        #pragma unroll
        for (int m = 1; m < 16; m <<= 1) {
            v0 += __shfl_xor(v0, m);
            v1 += __shfl_xor(v1, m);
        }
        if (cp == 0) {
            partials[((g * 16 + pb) * 32 + w) * 2 + 0] = v0;
            partials[((g * 16 + pb) * 32 + w) * 2 + 1] = v1;
        }
    }
}

__global__ void finalize(const float* __restrict__ partials, const float* __restrict__ fc_b,
                         float* __restrict__ out) {
    int tid = threadIdx.x;             // 256
    int b = tid >> 1, o = tid & 1;
    float s = fc_b[o];
    for (int w = 0; w < 32; ++w) s += partials[(b * 32 + w) * 2 + o];
    out[b * 2 + o] = s;
}

extern "C" void kernel_launch(void* const* d_in, const int* in_sizes, int n_in,
                              void* d_out, int out_size, void* d_ws, size_t ws_size,
                              hipStream_t stream) {
    const int*   x    = (const int*)d_in[0];
    const float* emb  = (const float*)d_in[1];
    const float* w_ih = (const float*)d_in[2];
    const float* w_hh = (const float*)d_in[3];
    const float* b_ih = (const float*)d_in[4];
    const float* b_hh = (const float*)d_in[5];
    const float* fc_w = (const float*)d_in[6];
    const float* fc_b = (const float*)d_in[7];
    float* out = (float*)d_out;
    char* ws = (char*)d_ws;

    if (ws_size < WS_NEEDED) {
        (void)hipMemsetAsync(d_out, 0xFF, (size_t)out_size * sizeof(float), stream);
        return;
    }

    unsigned*       slots   = (unsigned*)(ws);
    unsigned short* h_arr   = (unsigned short*)(ws + H_OFF);
    unsigned short* wh_arr  = (unsigned short*)(ws + WH_OFF);
    unsigned short* wi_arr  = (unsigned short*)(ws + WI_OFF);
    float*          bs_arr  = (float*)(ws + BS_OFF);
    float*          pt_arr  = (float*)(ws + PT_OFF);
    unsigned short* emb_arr = (unsigned short*)(ws + EMB_OFF);

    // zero the arrival slots (h buffers need no init: t=0 skips the h-MFMA)
    (void)hipMemsetAsync(ws, 0, SLOT_BYTES, stream);

    prep_wh  <<<2048, 256, 0, stream>>>(w_hh, wh_arr);
    prep_wi  <<<1024, 256, 0, stream>>>(w_ih, wi_arr);
    prep_bsum<<<16,   256, 0, stream>>>(b_ih, b_hh, bs_arr);
    prep_emb <<<16384,256, 0, stream>>>(x, emb, emb_arr);
    lstm_main<<<NWG, NTHR, 0, stream>>>(wh_arr, wi_arr, bs_arr, emb_arr, h_arr,
                                        fc_w, pt_arr, slots);
    finalize <<<1, 256, 0, stream>>>(pt_arr, fc_b, out);
}